// Round 12
// baseline (320.168 us; speedup 1.0000x reference)
//
#include <hip/hip_runtime.h>
#include <stdint.h>

// SimpleGCN, f32 in / f32 out. Round 12: push the confirmed barrier-count
// lever everywhere. G2: 512x128 tile (1024 thr, 16 waves, 80KB LDS, 2/CU) ->
// 32 barrier-iters/CU. F1/F2: BK=128 (64KB LDS, 2/CU) -> 32/16 barrier-iters.
//   conv: Fs,Ft,W1 -> f16; W2 -> bf16 (vectorized float4->uint2)
//   G2 : S = Fsf@Ftf^T (f16 MFMA); P~=exp(S-100)->bf16 [8192][8192] + rowsum partials
//   FIN: invl = 1/sum rsp
//   GY1: Y1T = W1f@Fsf^T (f16) -> bf16 [256][8192]     (BK=64 path)
//   F1 : pp[z] = invl(.)(P~ @ Y1) (bf16), split-K=4, f16 partials (BK=128)
//   C1 : x1 = sum4(pp) -> f32 d_out + bf16 x1h
//   GY2: Y2T = W2h@x1h^T (bf16) -> bf16 [128][8192]    (BK=64 path)
//   F2 : pp[z] = invl(.)(P~ @ Y2), split-K=8, f16 partials (BK=128)
//   C2 : x2 = sum8(pp) -> f32 d_out
// All NT GEMMs; LDS XOR-chunk swizzles keep ds_read conflicts at free 2-way.
// Epilogue coords from runtime MFMA layout probe (rmap/cmap).

typedef unsigned short u16;
typedef short bf16x8 __attribute__((ext_vector_type(8)));
typedef _Float16 f16x8 __attribute__((ext_vector_type(8)));
typedef float f32x4 __attribute__((ext_vector_type(4)));

#define EPI_STOREB 0
#define EPI_PARTH  1

__device__ __forceinline__ u16 f2bf(float f) {
  unsigned u = __float_as_uint(f);
  u += 0x7fffu + ((u >> 16) & 1u);
  return (u16)(u >> 16);
}
__device__ __forceinline__ u16 f2h(float f) {
  union { _Float16 h; u16 u; } cv; cv.h = (_Float16)f; return cv.u;
}
__device__ __forceinline__ float h2f(u16 u) {
  union { u16 u; _Float16 h; } cv; cv.u = u; return (float)cv.h;
}
__device__ __forceinline__ int swz8(int r) { return (r ^ (r >> 3)) & 7; }

__device__ __forceinline__ void async16(const void* g, void* lds) {
  __builtin_amdgcn_global_load_lds(
      (const __attribute__((address_space(1))) unsigned int*)g,
      (__attribute__((address_space(3))) unsigned int*)lds, 16, 0, 0);
}

// ---------------------------------------------------------------------------
__global__ void probe_layout(int* __restrict__ rmap, int* __restrict__ cmap) {
  const int lane = threadIdx.x & 63;
  const int t = lane & 15, quad = lane >> 4;
  bf16x8 avt, av1;
  const u16 bt = f2bf((float)t), b1 = 0x3f80;
#pragma unroll
  for (int j = 0; j < 8; ++j) { ((u16*)&avt)[j] = bt; ((u16*)&av1)[j] = b1; }
  f32x4 z = {0.f, 0.f, 0.f, 0.f};
  f32x4 r1 = __builtin_amdgcn_mfma_f32_16x16x32_bf16(avt, av1, z, 0, 0, 0);
  f32x4 r2 = __builtin_amdgcn_mfma_f32_16x16x32_bf16(av1, avt, z, 0, 0, 0);
  if (threadIdx.x < 64) {
#pragma unroll
    for (int e = 0; e < 4; ++e) {
      int r = (int)(r1[e] * 0.03125f + 0.5f);
      int c = (int)(r2[e] * 0.03125f + 0.5f);
      if (r < 0 || r > 15) r = quad * 4 + e;
      if (c < 0 || c > 15) c = t;
      rmap[lane * 4 + e] = r;
      cmap[lane * 4 + e] = c;
    }
  }
}

// ---------------------------------------------------------------------------
// Vectorized conversions: float4 in, 4 packed u16 (uint2) out.
// ---------------------------------------------------------------------------
__device__ __forceinline__ void cvt4h(const float4* in, uint2* out, int i) {
  float4 v = in[i];
  uint2 o;
  o.x = (unsigned)f2h(v.x) | ((unsigned)f2h(v.y) << 16);
  o.y = (unsigned)f2h(v.z) | ((unsigned)f2h(v.w) << 16);
  out[i] = o;
}
__device__ __forceinline__ void cvt4b(const float4* in, uint2* out, int i) {
  float4 v = in[i];
  uint2 o;
  o.x = (unsigned)f2bf(v.x) | ((unsigned)f2bf(v.y) << 16);
  o.y = (unsigned)f2bf(v.z) | ((unsigned)f2bf(v.w) << 16);
  out[i] = o;
}

__global__ __launch_bounds__(256) void conv_all(
    const float* __restrict__ Fs, const float* __restrict__ Ft,
    const float* __restrict__ W1, const float* __restrict__ W2,
    u16* __restrict__ Fsf, u16* __restrict__ Ftf,
    u16* __restrict__ W1f, u16* __restrict__ W2h) {
  const int bx = blockIdx.x, tid = threadIdx.x;
  if (bx < 1024) {
    for (int i = bx * 256 + tid; i < 1048576; i += 1024 * 256)
      cvt4h((const float4*)Fs, (uint2*)Fsf, i);
  } else if (bx < 2048) {
    for (int i = (bx - 1024) * 256 + tid; i < 1048576; i += 1024 * 256)
      cvt4h((const float4*)Ft, (uint2*)Ftf, i);
  } else if (bx < 2080) {
    for (int i = (bx - 2048) * 256 + tid; i < 32768; i += 32 * 256)
      cvt4h((const float4*)W1, (uint2*)W1f, i);
  } else {
    for (int i = (bx - 2080) * 256 + tid; i < 8192; i += 8 * 256)
      cvt4b((const float4*)W2, (uint2*)W2h, i);
  }
}

// ---------------------------------------------------------------------------
// G2: f16 NT GEMM, 512x128 tile, 1024 threads (16 waves), BK=64, swizzled LDS.
// exp epilogue + fused row-sum partials (lrs aliased onto dead lA).
// ---------------------------------------------------------------------------
__global__ __launch_bounds__(1024) void gemm_pexp_f16_512(
    const u16* __restrict__ A, const u16* __restrict__ B, int K, int N,
    u16* __restrict__ P, float* __restrict__ rsp,
    const int* __restrict__ rmap, const int* __restrict__ cmap) {
  __shared__ __align__(16) u16 lA[512 * 64];   // 64 KB, rows of 128 B
  __shared__ __align__(16) u16 lB[128 * 64];   // 16 KB
  float* lrs = (float*)lA;                     // [512][2], valid post-K-loop

  const int tid = threadIdx.x;
  const int wave = tid >> 6, lane = tid & 63;
  const int quad = lane >> 4, t = lane & 15;
  const int bm = blockIdx.y * 512, bn = blockIdx.x * 128;
  const int wm = (wave & 7) * 64, wn = (wave >> 3) * 64;

  f32x4 acc[4][4];
#pragma unroll
  for (int i = 0; i < 4; ++i)
#pragma unroll
    for (int j = 0; j < 4; ++j) acc[i][j] = (f32x4){0.f, 0.f, 0.f, 0.f};

  // staging: 1024 thr x 16B = 16 KB/call. A: 4 calls (128 rows each); B: 1.
  const int srow = tid >> 3, schk = tid & 7;
  const u16* pA[4]; const u16* pB0;
#pragma unroll
  for (int j = 0; j < 4; ++j) {
    const int r = j * 128 + srow;
    pA[j] = A + (size_t)(bm + r) * K + (schk ^ swz8(r)) * 8;
  }
  pB0 = B + (size_t)(bn + srow) * K + (schk ^ swz8(srow)) * 8;

  int aoffx[4], boffx[4];
#pragma unroll
  for (int i = 0; i < 4; ++i) {
    const int rm = wm + i * 16 + t;
    aoffx[i] = rm * 128 + (swz8(rm) << 4);
    const int rn = wn + i * 16 + t;
    boffx[i] = rn * 128 + (swz8(rn) << 4);
  }
  const int sq0 = quad << 4, sq1 = (quad << 4) | 64;

  for (int k0 = 0; k0 < K; k0 += 64) {
#pragma unroll
    for (int j = 0; j < 4; ++j) {
      async16(pA[j], (char*)lA + j * 16384 + wave * 1024);
      pA[j] += 64;
    }
    async16(pB0, (char*)lB + wave * 1024);
    pB0 += 64;
    __syncthreads();
#pragma unroll
    for (int s = 0; s < 2; ++s) {
      const int sq = s ? sq1 : sq0;
      f16x8 av[4], bv[4];
#pragma unroll
      for (int i = 0; i < 4; ++i) {
        av[i] = *(const f16x8*)((const char*)lA + (aoffx[i] ^ sq));
        bv[i] = *(const f16x8*)((const char*)lB + (boffx[i] ^ sq));
      }
#pragma unroll
      for (int mi = 0; mi < 4; ++mi)
#pragma unroll
        for (int ni = 0; ni < 4; ++ni)
          acc[mi][ni] = __builtin_amdgcn_mfma_f32_16x16x32_f16(av[mi], bv[ni], acc[mi][ni], 0, 0, 0);
    }
    __syncthreads();
  }

  int rl[4], cl[4];
#pragma unroll
  for (int e = 0; e < 4; ++e) {
    rl[e] = rmap[lane * 4 + e];
    cl[e] = cmap[lane * 4 + e];
  }
#pragma unroll
  for (int mi = 0; mi < 4; ++mi)
#pragma unroll
    for (int e = 0; e < 4; ++e) {
      const int rloc = wm + mi * 16 + rl[e];
      const int row = bm + rloc;
      float s = 0.f;
#pragma unroll
      for (int ni = 0; ni < 4; ++ni) {
        float p = __expf(acc[mi][ni][e] - 100.0f);
        s += p;
        P[(size_t)row * N + (bn + wn + ni * 16 + cl[e])] = f2bf(p);
      }
      s += __shfl_xor(s, 1, 64);
      s += __shfl_xor(s, 2, 64);
      s += __shfl_xor(s, 4, 64);
      s += __shfl_xor(s, 8, 64);
      if (t == 0) lrs[rloc * 2 + (wave >> 3)] = s;   // no race: wm x (wave>>3) unique
    }
  __syncthreads();
  if (tid < 512)
    rsp[(size_t)blockIdx.x * 8192 + bm + tid] = lrs[tid * 2] + lrs[tid * 2 + 1];
}

__global__ __launch_bounds__(256) void finalize_invl(
    const float* __restrict__ rsp, float* __restrict__ invl) {
  const int row = blockIdx.x * 256 + threadIdx.x;
  float s = 0.f;
#pragma unroll 8
  for (int b = 0; b < 64; ++b) s += rsp[(size_t)b * 8192 + row];
  invl[row] = 1.0f / s;
}

// ---------------------------------------------------------------------------
// BK=128 NT GEMM, 128x128 tile, 256 thr; bf16; EPI_PARTH epilogue.
// LDS rows 256B, 16-chunk swizzle slot = c ^ (r&15) -> reads are free 2-way.
// ---------------------------------------------------------------------------
__global__ __launch_bounds__(256) void gemm_nt128(
    const u16* __restrict__ A, const u16* __restrict__ B, int K, int Kc, int N,
    u16* __restrict__ outp, const float* __restrict__ invl,
    const int* __restrict__ rmap, const int* __restrict__ cmap) {
  __shared__ __align__(16) u16 lA[128 * 128];  // 32 KB
  __shared__ __align__(16) u16 lB[128 * 128];  // 32 KB

  const int tid = threadIdx.x;
  const int wave = tid >> 6, lane = tid & 63;
  const int quad = lane >> 4, t = lane & 15;
  const int bm = blockIdx.y * 128, bn = blockIdx.x * 128;
  const int wm = (wave & 1) * 64, wn = (wave >> 1) * 64;
  const int koff = blockIdx.z * Kc;

  f32x4 acc[4][4];
#pragma unroll
  for (int i = 0; i < 4; ++i)
#pragma unroll
    for (int j = 0; j < 4; ++j) acc[i][j] = (f32x4){0.f, 0.f, 0.f, 0.f};

  // staging: 256 thr x 16B = 4 KB/call = 16 rows. 8 calls each for A and B.
  const int srow = tid >> 4, schk = tid & 15;       // srow = r & 15
  const int scol = (schk ^ srow) * 8;
  const u16* pA[8]; const u16* pB[8];
#pragma unroll
  for (int j = 0; j < 8; ++j) {
    pA[j] = A + (size_t)(bm + j * 16 + srow) * K + koff + scol;
    pB[j] = B + (size_t)(bn + j * 16 + srow) * K + koff + scol;
  }

  int abase[4], bbase[4], arx[4], brx[4];
#pragma unroll
  for (int i = 0; i < 4; ++i) {
    const int rm = wm + i * 16 + t;
    abase[i] = rm * 256; arx[i] = rm & 15;
    const int rn = wn + i * 16 + t;
    bbase[i] = rn * 256; brx[i] = rn & 15;
  }

  const int iters = Kc >> 7;
  for (int it = 0; it < iters; ++it) {
#pragma unroll
    for (int j = 0; j < 8; ++j) {
      async16(pA[j], (char*)lA + j * 4096 + wave * 1024);
      async16(pB[j], (char*)lB + j * 4096 + wave * 1024);
      pA[j] += 128; pB[j] += 128;
    }
    __syncthreads();
#pragma unroll
    for (int s = 0; s < 4; ++s) {
      const int c = (s << 2) | quad;
      bf16x8 av[4], bv[4];
#pragma unroll
      for (int i = 0; i < 4; ++i) {
        av[i] = *(const bf16x8*)((const char*)lA + abase[i] + ((c ^ arx[i]) << 4));
        bv[i] = *(const bf16x8*)((const char*)lB + bbase[i] + ((c ^ brx[i]) << 4));
      }
#pragma unroll
      for (int mi = 0; mi < 4; ++mi)
#pragma unroll
        for (int ni = 0; ni < 4; ++ni)
          acc[mi][ni] = __builtin_amdgcn_mfma_f32_16x16x32_bf16(av[mi], bv[ni], acc[mi][ni], 0, 0, 0);
    }
    __syncthreads();
  }

  int rl[4], cl[4];
#pragma unroll
  for (int e = 0; e < 4; ++e) {
    rl[e] = rmap[lane * 4 + e];
    cl[e] = cmap[lane * 4 + e];
  }
  const size_t zoff = (size_t)blockIdx.z * ((size_t)gridDim.y * 128) * N;
#pragma unroll
  for (int mi = 0; mi < 4; ++mi)
#pragma unroll
    for (int e = 0; e < 4; ++e) {
      const int row = bm + wm + mi * 16 + rl[e];
      const float sc = invl[row];
#pragma unroll
      for (int ni = 0; ni < 4; ++ni) {
        const size_t idx = (size_t)row * N + (bn + wn + ni * 16 + cl[e]);
        outp[zoff + idx] = f2h(acc[mi][ni][e] * sc);
      }
    }
}

// ---------------------------------------------------------------------------
// BK=64 NT GEMM 128x128 (r9/r11 proven) — used for GY1/GY2 (small K).
// ---------------------------------------------------------------------------
template <int F16>
__global__ __launch_bounds__(256) void gemm_nt(
    const u16* __restrict__ A, const u16* __restrict__ B, int K, int N,
    u16* __restrict__ outp,
    const int* __restrict__ rmap, const int* __restrict__ cmap) {
  __shared__ __align__(16) u16 lA[128 * 64];
  __shared__ __align__(16) u16 lB[128 * 64];

  const int tid = threadIdx.x;
  const int wave = tid >> 6, lane = tid & 63;
  const int quad = lane >> 4, t = lane & 15;
  const int bm = blockIdx.y * 128, bn = blockIdx.x * 128;
  const int wm = (wave & 1) * 64, wn = (wave >> 1) * 64;

  f32x4 acc[4][4];
#pragma unroll
  for (int i = 0; i < 4; ++i)
#pragma unroll
    for (int j = 0; j < 4; ++j) acc[i][j] = (f32x4){0.f, 0.f, 0.f, 0.f};

  const int srow = tid >> 3, schk = tid & 7;
  const u16* pA[4]; const u16* pB[4];
#pragma unroll
  for (int j = 0; j < 4; ++j) {
    const int r = j * 32 + srow;
    const int c = schk ^ swz8(r);
    pA[j] = A + (size_t)(bm + r) * K + c * 8;
    pB[j] = B + (size_t)(bn + r) * K + c * 8;
  }

  int aoffx[4], boffx[4];
#pragma unroll
  for (int i = 0; i < 4; ++i) {
    const int rm = wm + i * 16 + t;
    aoffx[i] = rm * 128 + (swz8(rm) << 4);
    const int rn = wn + i * 16 + t;
    boffx[i] = rn * 128 + (swz8(rn) << 4);
  }
  const int sq0 = quad << 4, sq1 = (quad << 4) | 64;

  for (int k0 = 0; k0 < K; k0 += 64) {
#pragma unroll
    for (int j = 0; j < 4; ++j) {
      async16(pA[j], (char*)lA + j * 4096 + wave * 1024);
      async16(pB[j], (char*)lB + j * 4096 + wave * 1024);
      pA[j] += 64; pB[j] += 64;
    }
    __syncthreads();
#pragma unroll
    for (int s = 0; s < 2; ++s) {
      const int sq = s ? sq1 : sq0;
      bf16x8 av[4], bv[4];
#pragma unroll
      for (int i = 0; i < 4; ++i) {
        av[i] = *(const bf16x8*)((const char*)lA + (aoffx[i] ^ sq));
        bv[i] = *(const bf16x8*)((const char*)lB + (boffx[i] ^ sq));
      }
#pragma unroll
      for (int mi = 0; mi < 4; ++mi)
#pragma unroll
        for (int ni = 0; ni < 4; ++ni) {
          if constexpr (F16)
            acc[mi][ni] = __builtin_amdgcn_mfma_f32_16x16x32_f16(
                __builtin_bit_cast(f16x8, av[mi]), __builtin_bit_cast(f16x8, bv[ni]),
                acc[mi][ni], 0, 0, 0);
          else
            acc[mi][ni] = __builtin_amdgcn_mfma_f32_16x16x32_bf16(av[mi], bv[ni], acc[mi][ni], 0, 0, 0);
        }
    }
    __syncthreads();
  }

  int rl[4], cl[4];
#pragma unroll
  for (int e = 0; e < 4; ++e) {
    rl[e] = rmap[lane * 4 + e];
    cl[e] = cmap[lane * 4 + e];
  }
#pragma unroll
  for (int mi = 0; mi < 4; ++mi)
#pragma unroll
    for (int e = 0; e < 4; ++e) {
      const int row = bm + wm + mi * 16 + rl[e];
#pragma unroll
      for (int ni = 0; ni < 4; ++ni)
        outp[(size_t)row * N + (bn + wn + ni * 16 + cl[e])] = f2bf(acc[mi][ni][e]);
    }
}

// ---------------------------------------------------------------------------
__global__ __launch_bounds__(256) void combine1(
    const u16* __restrict__ pp, const float* __restrict__ invl,
    float* __restrict__ x1f, u16* __restrict__ x1h) {
  const int row = blockIdx.x, j = threadIdx.x;
  const size_t i = (size_t)row * 256 + j;
  const float v = h2f(pp[i]) + h2f(pp[2097152 + i]) +
                  h2f(pp[4194304 + i]) + h2f(pp[6291456 + i]);
  x1f[i] = v;
  x1h[i] = f2bf(v);
}

__global__ __launch_bounds__(128) void combine2(
    const u16* __restrict__ pp, const float* __restrict__ invl,
    float* __restrict__ x2f) {
  const int row = blockIdx.x, j = threadIdx.x;
  const size_t i = (size_t)row * 128 + j;
  float s = 0.f;
#pragma unroll
  for (int z = 0; z < 8; ++z) s += h2f(pp[(size_t)z * 1048576 + i]);
  x2f[i] = s;
}

// ---------------------------------------------------------------------------
extern "C" void kernel_launch(void* const* d_in, const int* in_sizes, int n_in,
                              void* d_out, int out_size, void* d_ws, size_t ws_size,
                              hipStream_t stream) {
  const float* Fs = (const float*)d_in[0];   // [8192][512]
  const float* Ft = (const float*)d_in[1];   // [8192][512]
  const float* W1 = (const float*)d_in[2];   // [256][512]
  const float* W2 = (const float*)d_in[3];   // [128][256]

  char* ws = (char*)d_ws;                    // extent <= 168134656 (proven)
  u16*   P    = (u16*)(ws);                  // [8192][8192] bf16, 0..128MiB
  u16*   Fsf  = (u16*)(ws + 134217728);      // 8MiB f16 (dead after GY1)
  u16*   Ftf  = (u16*)(ws + 142606336);      // 8MiB f16 (dead after G2)
  u16*   pp   = (u16*)(ws + 134217728);      // 16MiB f16 partials (born F1)
  float* rsp  = (float*)(ws + 150994944);    // [64][8192] f32 2MiB (dead after FIN)
  u16*   Y1T  = (u16*)(ws + 153091200);      // [256][8192] 4MiB
  u16*   x1h  = (u16*)(ws + 157286400);      // [8192][256] 4MiB
  u16*   Y2T  = (u16*)(ws + 161480704);      // [128][8192] 2MiB
  float* invl = (float*)(ws + 163577856);    // [8192]
  int*   rmap = (int*)  (ws + 163610624);
  int*   cmap = (int*)  (ws + 163611648);
  u16*   W1f  = (u16*)(ws + 163612672);      // [256][512] f16 256KiB
  u16*   W2h  = (u16*)(ws + 163874816);      // [128][256] bf16 64KiB

  float* x1f = (float*)d_out;                // [8192][256]
  float* x2f = (float*)d_out + 2097152;      // [8192][128]

  dim3 blk(256);
  probe_layout<<<1, 64, 0, stream>>>(rmap, cmap);
  conv_all<<<2088, blk, 0, stream>>>(Fs, Ft, W1, W2, Fsf, Ftf, W1f, W2h);
  // G2: P~ = exp(f16 S - 100) + fused row-sum partials (512x128 tile)
  gemm_pexp_f16_512<<<dim3(64, 16), dim3(1024), 0, stream>>>(
      Fsf, Ftf, 512, 8192, P, rsp, rmap, cmap);
  finalize_invl<<<32, blk, 0, stream>>>(rsp, invl);
  // GY1: Y1T = W1f @ Fsf^T (f16)
  gemm_nt<1><<<dim3(64, 2), blk, 0, stream>>>(W1f, Fsf, 512, 8192, Y1T, rmap, cmap);
  // F1: pp[z] = invl(.)(P~ @ Y1), split-K=4 (Kc=2048), BK=128
  gemm_nt128<<<dim3(2, 64, 4), blk, 0, stream>>>(P, Y1T, 8192, 2048, 256,
                                                 pp, invl, rmap, cmap);
  combine1<<<8192, blk, 0, stream>>>(pp, invl, x1f, x1h);
  // GY2: Y2T = W2h @ x1h^T (bf16)
  gemm_nt<0><<<dim3(64, 1), blk, 0, stream>>>(W2h, x1h, 256, 8192, Y2T, rmap, cmap);
  // F2: pp[z] = invl(.)(P~ @ Y2), split-K=8 (Kc=1024), BK=128
  gemm_nt128<<<dim3(1, 64, 8), blk, 0, stream>>>(P, Y2T, 8192, 1024, 128,
                                                 pp, invl, rmap, cmap);
  combine2<<<8192, dim3(128), 0, stream>>>(pp, invl, x2f);
}